// Round 1
// baseline (5351.990 us; speedup 1.0000x reference)
//
#include <hip/hip_runtime.h>
#include <cstdint>
#include <cstddef>

// ---- problem constants ----
#define NN     20000
#define FIN_D  64
#define H_D    128
#define M_D    16
#define EIA_D  256000
#define EIR_D  256000
#define EIT_D  100000
#define EIN_D  257
#define EHID_D 514
#define NIN_D  144
#define NHID_D 256
#define E1TOT  (EIA_D + NN)   // intra edges + self loops

__device__ __forceinline__ float siluf(float x) { return x / (1.f + __expf(-x)); }
__device__ __forceinline__ float reluf(float x) { return x > 0.f ? x : 0.f; }

// order-preserving float<->uint encoding for atomicMax-based segment max
__device__ __forceinline__ unsigned enc_f(float f) {
    unsigned u = __float_as_uint(f);
    return (u & 0x80000000u) ? ~u : (u | 0x80000000u);
}
__device__ __forceinline__ float dec_f(unsigned e) {
    return (e & 0x80000000u) ? __uint_as_float(e & 0x7FFFFFFFu) : __uint_as_float(~e);
}
#define ENC_NEG_INF 0x007FFFFFu   // enc(-inf)

// ---------------- utility kernels ----------------
__global__ void k_fill(float* p, float v, int n) {
    int i = blockIdx.x * 256 + threadIdx.x; if (i < n) p[i] = v;
}
__global__ void k_fillu(unsigned* p, unsigned v, int n) {
    int i = blockIdx.x * 256 + threadIdx.x; if (i < n) p[i] = v;
}
__global__ void k_copy(float* d, const float* s, int n) {
    int i = blockIdx.x * 256 + threadIdx.x; if (i < n) d[i] = s[i];
}
__global__ void k_relu(float* p, int n) {
    int i = blockIdx.x * 256 + threadIdx.x; if (i < n) p[i] = reluf(p[i]);
}
__global__ void k_bias_init(float* out, const float* __restrict__ b, int n) {
    int i = blockIdx.x * 256 + threadIdx.x; if (i < n) out[i] = b[i & (H_D - 1)];
}
__global__ void k_concat(float* __restrict__ cat, const float* __restrict__ f,
                         const float* __restrict__ m, int n) {
    int i = blockIdx.x * 256 + threadIdx.x;
    if (i >= n * NIN_D) return;
    int r = i / NIN_D, c = i - r * NIN_D;
    cat[i] = (c < H_D) ? f[r * H_D + c] : m[r * M_D + (c - H_D)];
}

// ---------------- generic fp32 tiled GEMM: C = act(A@W + bias) (+res) ----------------
// 64x64 tile, 256 threads, 4x4 micro-tile, K-step 16.
template<int ACT, bool RES>
__global__ __launch_bounds__(256) void k_gemm(const float* __restrict__ A, const float* __restrict__ W,
                                              const float* __restrict__ bias, const float* __restrict__ res,
                                              float* __restrict__ C, int M, int Nc, int K) {
    __shared__ __align__(16) float sA[16][68];   // [k][m], row stride 272B (16B-aligned)
    __shared__ __align__(16) float sB[16][68];   // [k][n]
    const int tid = threadIdx.x;
    const int bm = blockIdx.x * 64, bn = blockIdx.y * 64;
    const int tm = (tid >> 4) << 2, tn = (tid & 15) << 2;
    float acc[4][4] = {};
    for (int k0 = 0; k0 < K; k0 += 16) {
#pragma unroll
        for (int t = 0; t < 4; ++t) {
            int idx = tid + 256 * t;
            int m = idx >> 4, kk = idx & 15;
            int gm = bm + m, gk = k0 + kk;
            sA[kk][m] = (gm < M && gk < K) ? A[(size_t)gm * K + gk] : 0.f;
            int n2 = idx & 63, k2 = idx >> 6;
            int gn = bn + n2, gk2 = k0 + k2;
            sB[k2][n2] = (gn < Nc && gk2 < K) ? W[(size_t)gk2 * Nc + gn] : 0.f;
        }
        __syncthreads();
#pragma unroll
        for (int kk = 0; kk < 16; ++kk) {
            float4 av = *(const float4*)&sA[kk][tm];
            float4 bv = *(const float4*)&sB[kk][tn];
            float aa[4] = {av.x, av.y, av.z, av.w};
            float bb[4] = {bv.x, bv.y, bv.z, bv.w};
#pragma unroll
            for (int i = 0; i < 4; ++i)
#pragma unroll
                for (int j = 0; j < 4; ++j) acc[i][j] += aa[i] * bb[j];
        }
        __syncthreads();
    }
#pragma unroll
    for (int i = 0; i < 4; ++i) {
        int gm = bm + tm + i;
        if (gm >= M) continue;
#pragma unroll
        for (int j = 0; j < 4; ++j) {
            int gn = bn + tn + j;
            if (gn >= Nc) continue;
            float v = acc[i][j];
            if (bias) v += bias[gn];
            if (ACT == 1) v = reluf(v);
            if (ACT == 2) v = siluf(v);
            if (RES) v += res[(size_t)gm * Nc + gn];
            C[(size_t)gm * Nc + gn] = v;
        }
    }
}

// ---------------- row dot (es/ed): wave per node, d fixed at 128 ----------------
__global__ void k_rowdot(const float* __restrict__ h, const float* __restrict__ a,
                         float* __restrict__ o, int n) {
    int w = (blockIdx.x * blockDim.x + threadIdx.x) >> 6;
    int lane = threadIdx.x & 63;
    if (w >= n) return;
    const float* r = h + (size_t)w * H_D;
    float s = r[lane] * a[lane] + r[lane + 64] * a[lane + 64];
#pragma unroll
    for (int off = 32; off; off >>= 1) s += __shfl_xor(s, off);
    if (lane == 0) o[w] = s;
}

__global__ void k_nodescore(const float* __restrict__ x, const float* __restrict__ wv,
                            const float* __restrict__ b, float* __restrict__ o, int n) {
    int w = (blockIdx.x * blockDim.x + threadIdx.x) >> 6;
    int lane = threadIdx.x & 63;
    if (w >= n) return;
    const float* r = x + (size_t)w * H_D;
    float s = r[lane] * wv[lane] + r[lane + 64] * wv[lane + 64];
#pragma unroll
    for (int off = 32; off; off >>= 1) s += __shfl_xor(s, off);
    if (lane == 0) o[w] = s + b[0];
}

// ---------------- GAT edge kernels ----------------
// e in [0,nE): edge from list. e in [nE,nTot): self loop j=i=e-nE.
__global__ void k_gat_max(const int* __restrict__ sj, const int* __restrict__ si, int nE, int nTot,
                          const float* __restrict__ es, const float* __restrict__ ed, unsigned* __restrict__ mx) {
    int e = blockIdx.x * 256 + threadIdx.x;
    if (e >= nTot) return;
    int j, i;
    if (e < nE) { j = sj[e]; i = si[e]; } else { j = i = e - nE; }
    float v = es[j] + ed[i];
    v = v < 0.f ? 0.2f * v : v;
    atomicMax(mx + i, enc_f(v));
}

__global__ void k_gat_den(const int* __restrict__ sj, const int* __restrict__ si, int nE, int nTot,
                          const float* __restrict__ es, const float* __restrict__ ed,
                          const unsigned* __restrict__ mx, float* __restrict__ ebuf, float* __restrict__ den) {
    int e = blockIdx.x * 256 + threadIdx.x;
    if (e >= nTot) return;
    int j, i;
    if (e < nE) { j = sj[e]; i = si[e]; } else { j = i = e - nE; }
    float v = es[j] + ed[i];
    v = v < 0.f ? 0.2f * v : v;
    float ex = __expf(v - dec_f(mx[i]));
    ebuf[e] = ex;
    atomicAdd(den + i, ex);
}

// wave per edge: 128 channels, 2 per lane, atomic scatter into out
__global__ __launch_bounds__(256) void k_gat_agg(const int* __restrict__ sj, const int* __restrict__ si,
                                                 int nE, int nTot,
                                                 const float* __restrict__ hs, const float* __restrict__ ebuf,
                                                 const float* __restrict__ den, float* __restrict__ out) {
    int e = blockIdx.x * 4 + (threadIdx.x >> 6);
    int lane = threadIdx.x & 63;
    if (e >= nTot) return;
    int j, i;
    if (e < nE) { j = sj[e]; i = si[e]; } else { j = i = e - nE; }
    float alpha = ebuf[e] / (den[i] + 1e-16f);
    const float* hr = hs + (size_t)j * H_D;
    float* orow = out + (size_t)i * H_D;
    atomicAdd(orow + lane, alpha * hr[lane]);
    atomicAdd(orow + lane + 64, alpha * hr[lane + 64]);
}

// ---------------- EGNN fused edge kernel (wave per edge, grid-stride) ----------------
__global__ __launch_bounds__(256) void k_egnn_edge(
        const int* __restrict__ sj, const int* __restrict__ si, int nE,
        const float* __restrict__ A, const float* __restrict__ B, const float* __restrict__ coors,
        const float* __restrict__ w_rd, const float* __restrict__ eb1,
        const float* __restrict__ ew2, const float* __restrict__ eb2,
        const float* __restrict__ cw1, const float* __restrict__ cb1,
        const float* __restrict__ cw2, const float* __restrict__ cb2,
        float* __restrict__ cacc, float* __restrict__ macc) {
    __shared__ float s_ew2t[M_D * EHID_D];   // transposed [c][k] -> conflict-free reads
    __shared__ float s_wrd[EHID_D], s_eb1[EHID_D];
    __shared__ float s_cw1[M_D * 64], s_cb1[64], s_cw2[64], s_eb2[M_D];
    for (int t = threadIdx.x; t < EHID_D * M_D; t += 256) {
        int k = t >> 4, c = t & 15;
        s_ew2t[c * EHID_D + k] = ew2[t];
    }
    for (int t = threadIdx.x; t < EHID_D; t += 256) { s_wrd[t] = w_rd[t]; s_eb1[t] = eb1[t]; }
    for (int t = threadIdx.x; t < M_D * 64; t += 256) s_cw1[t] = cw1[t];
    if (threadIdx.x < 64) { s_cb1[threadIdx.x] = cb1[threadIdx.x]; s_cw2[threadIdx.x] = cw2[threadIdx.x]; }
    if (threadIdx.x < M_D) s_eb2[threadIdx.x] = eb2[threadIdx.x];
    __syncthreads();
    const float cb2v = cb2[0];
    const int lane = threadIdx.x & 63;
    const int wid = blockIdx.x * 4 + (threadIdx.x >> 6);
    const int nw = gridDim.x * 4;
    for (int e = wid; e < nE; e += nw) {
        int j = sj[e], i = si[e];
        float r0 = coors[j * 3 + 0] - coors[i * 3 + 0];
        float r1 = coors[j * 3 + 1] - coors[i * 3 + 1];
        float r2 = coors[j * 3 + 2] - coors[i * 3 + 2];
        float rd = r0 * r0 + r1 * r1 + r2 * r2;
        const float* Ar = A + (size_t)i * EHID_D;
        const float* Br = B + (size_t)j * EHID_D;
        float mc[M_D];
#pragma unroll
        for (int c = 0; c < M_D; ++c) mc[c] = 0.f;
        for (int k = lane; k < EHID_D; k += 64) {
            float h = Ar[k] + Br[k] + rd * s_wrd[k] + s_eb1[k];
            float sg = siluf(h);
#pragma unroll
            for (int c = 0; c < M_D; ++c) mc[c] += sg * s_ew2t[c * EHID_D + k];
        }
#pragma unroll
        for (int c = 0; c < M_D; ++c) {
            float v = mc[c];
#pragma unroll
            for (int off = 32; off; off >>= 1) v += __shfl_xor(v, off);
            mc[c] = siluf(v + s_eb2[c]);   // m_c, on all lanes
        }
        // coordinate gate: lane = hidden unit of cw-MLP (64 wide)
        float accp = s_cb1[lane];
#pragma unroll
        for (int c = 0; c < M_D; ++c) accp += mc[c] * s_cw1[c * 64 + lane];
        float p = siluf(accp) * s_cw2[lane];
#pragma unroll
        for (int off = 32; off; off >>= 1) p += __shfl_xor(p, off);
        float cw = p + cb2v;
        if (lane < 3) {
            float rv = lane == 0 ? r0 : (lane == 1 ? r1 : r2);
            atomicAdd(&cacc[(size_t)i * 3 + lane], cw * rv);
        }
        if (lane < M_D) {
            float mv = mc[0];
#pragma unroll
            for (int c = 1; c < M_D; ++c) if (lane == c) mv = mc[c];
            atomicAdd(&macc[(size_t)i * M_D + lane], mv);
        }
    }
}

// ---------------- aux head: fused gather-concat GEMM + relu + matvec ----------------
// block: 32 edges x 128 hidden, K=256 (128 from x1[i0], 128 from x2[i1]); then dot with w2.
__global__ __launch_bounds__(256) void k_aux(const float* __restrict__ x1, const float* __restrict__ x2,
                                             const int* __restrict__ i0, const int* __restrict__ i1,
                                             const float* __restrict__ w1, const float* __restrict__ b1,
                                             const float* __restrict__ w2, const float* __restrict__ b2,
                                             float* __restrict__ dist, int nE) {
    __shared__ __align__(16) float sX[32][33];
    __shared__ __align__(16) float sW[32][128];
    __shared__ __align__(16) float sH[32][129];
    const int tid = threadIdx.x;
    const int te = (tid >> 5) << 2;   // 0..28
    const int tn = (tid & 31) << 2;   // 0..124
    const int be = blockIdx.x * 32;
    float acc[4][4] = {};
    for (int k0 = 0; k0 < 256; k0 += 32) {
#pragma unroll
        for (int t = 0; t < 4; ++t) {
            int idx = tid + 256 * t;
            int m = idx >> 5, k = idx & 31;
            int ge = be + m, gk = k0 + k;
            float v = 0.f;
            if (ge < nE)
                v = (gk < 128) ? x1[(size_t)i0[ge] * H_D + gk]
                               : x2[(size_t)i1[ge] * H_D + (gk - 128)];
            sX[m][k] = v;
        }
#pragma unroll
        for (int t = 0; t < 16; ++t) {
            int idx = tid + 256 * t;
            int k = idx >> 7, n = idx & 127;
            sW[k][n] = w1[(size_t)(k0 + k) * 128 + n];
        }
        __syncthreads();
#pragma unroll
        for (int k = 0; k < 32; ++k) {
            float aa[4] = {sX[te][k], sX[te + 1][k], sX[te + 2][k], sX[te + 3][k]};
            float4 bv = *(const float4*)&sW[k][tn];
            float bb[4] = {bv.x, bv.y, bv.z, bv.w};
#pragma unroll
            for (int i = 0; i < 4; ++i)
#pragma unroll
                for (int j = 0; j < 4; ++j) acc[i][j] += aa[i] * bb[j];
        }
        __syncthreads();
    }
#pragma unroll
    for (int i = 0; i < 4; ++i)
#pragma unroll
        for (int j = 0; j < 4; ++j)
            sH[te + i][tn + j] = reluf(acc[i][j] + b1[tn + j]);
    __syncthreads();
    const int wv = tid >> 6, lane = tid & 63;
    for (int r = wv; r < 32; r += 4) {
        int ge = be + r;
        if (ge >= nE) continue;
        float s = sH[r][lane] * w2[lane] + sH[r][lane + 64] * w2[lane + 64];
#pragma unroll
        for (int off = 32; off; off >>= 1) s += __shfl_xor(s, off);
        if (lane == 0) dist[ge] = reluf(s + b2[0]);
    }
}

// ---------------- host ----------------
extern "C" void kernel_launch(void* const* d_in, const int* in_sizes, int n_in,
                              void* d_out, int out_size, void* d_ws, size_t ws_size,
                              hipStream_t stream) {
    const float* x1_in = (const float*)d_in[0];
    const float* x2_in = (const float*)d_in[1];
    const float* pos1  = (const float*)d_in[2];
    const float* pos2  = (const float*)d_in[3];
    const int* ei_intra1 = (const int*)d_in[4];
    const int* ei_intra2 = (const int*)d_in[5];
    const int* ei_12 = (const int*)d_in[6];
    const int* ei_21 = (const int*)d_in[7];
    const int* ei_int = (const int*)d_in[8];
    const float* g0_w  = (const float*)d_in[9];
    const float* g0_as = (const float*)d_in[10];
    const float* g0_ad = (const float*)d_in[11];
    const float* g0_b  = (const float*)d_in[12];
    const float* g1_w  = (const float*)d_in[13];
    const float* g1_as = (const float*)d_in[14];
    const float* g1_ad = (const float*)d_in[15];
    const float* g1_b  = (const float*)d_in[16];
    const float* it_ws = (const float*)d_in[17];
    const float* it_wd = (const float*)d_in[18];
    const float* it_as = (const float*)d_in[19];
    const float* it_ad = (const float*)d_in[20];
    const float* it_b  = (const float*)d_in[21];
    const float* eg_e_w1 = (const float*)d_in[22];
    const float* eg_e_b1 = (const float*)d_in[23];
    const float* eg_e_w2 = (const float*)d_in[24];
    const float* eg_e_b2 = (const float*)d_in[25];
    const float* eg_c_w1 = (const float*)d_in[26];
    const float* eg_c_b1 = (const float*)d_in[27];
    const float* eg_c_w2 = (const float*)d_in[28];
    const float* eg_c_b2 = (const float*)d_in[29];
    const float* eg_n_w1 = (const float*)d_in[30];
    const float* eg_n_b1 = (const float*)d_in[31];
    const float* eg_n_w2 = (const float*)d_in[32];
    const float* eg_n_b2 = (const float*)d_in[33];
    const float* lin_w = (const float*)d_in[34];
    const float* lin_b = (const float*)d_in[35];
    const float* aux_w1 = (const float*)d_in[36];
    const float* aux_b1 = (const float*)d_in[37];
    const float* aux_w2 = (const float*)d_in[38];
    const float* aux_b2 = (const float*)d_in[39];
    float* dout = (float*)d_out;

    // ---- workspace layout (floats), ~149 MB ----
    float* wsf = (float*)d_ws;
    size_t off = 0;
    auto alloc = [&](size_t nfl) { float* p = wsf + off; off += (nfl + 255) & ~(size_t)255; return p; };
    float* x1a = alloc((size_t)NN * H_D);
    float* x2a = alloc((size_t)NN * H_D);
    float* x1b = alloc((size_t)NN * H_D);
    float* x2b = alloc((size_t)NN * H_D);
    float* gatbuf = alloc((size_t)2 * NN * H_D);   // hs|hd ; also aliased as concat buf (N*144)
    float* hsب_unused = nullptr; (void)hsب_unused;
    float* hs = gatbuf;
    float* hd = gatbuf + (size_t)NN * H_D;
    float* esb = alloc(NN);
    float* edb = alloc(NN);
    unsigned* mx = (unsigned*)alloc(NN);
    float* den = alloc(NN);
    float* ebuf = alloc(E1TOT);
    float* co1a = alloc(NN * 3);
    float* co1b = alloc(NN * 3);
    float* co2a = alloc(NN * 3);
    float* co2b = alloc(NN * 3);
    float* macc = alloc((size_t)NN * M_D);
    float* Abuf = alloc((size_t)NN * EHID_D);
    float* Bbuf = alloc((size_t)NN * EHID_D);
    float* catb = gatbuf;          // N*144 fits in 2*N*128 (GAT bufs free during EGNN node MLP)
    float* nh   = Abuf;            // N*256 fits in N*514 (A free once edge kernel done)

    const int N = NN, H = H_D;
    dim3 gemm_grid_h((N + 63) / 64, (H + 63) / 64);
    dim3 gemm_grid_A((N + 63) / 64, (EHID_D + 63) / 64);
    dim3 gemm_grid_nh((N + 63) / 64, (NHID_D + 63) / 64);
    int gN = (N + 255) / 256;
    int gNH = (N * H + 255) / 256;
    int gNW = (N + 3) / 4;         // wave-per-node blocks

    // ---- GAT stage ----
    auto gat = [&](const float* xsrc, const float* xdst, bool same,
                   const int* eiBase, int nE, bool self,
                   const float* wsrc, const float* wdst,
                   const float* as_, const float* ad_, const float* b_,
                   int K, float* outb) {
        const int* sj = eiBase;
        const int* si = eiBase + nE;
        int nTot = nE + (self ? N : 0);
        k_gemm<0, false><<<gemm_grid_h, 256, 0, stream>>>(xsrc, wsrc, nullptr, nullptr, hs, N, H, K);
        const float* hdp = hs;
        if (!same) {
            k_gemm<0, false><<<gemm_grid_h, 256, 0, stream>>>(xdst, wdst, nullptr, nullptr, hd, N, H, K);
            hdp = hd;
        }
        k_rowdot<<<gNW, 256, 0, stream>>>(hs, as_, esb, N);
        k_rowdot<<<gNW, 256, 0, stream>>>(hdp, ad_, edb, N);
        k_fillu<<<gN, 256, 0, stream>>>(mx, ENC_NEG_INF, N);
        k_fill<<<gN, 256, 0, stream>>>(den, 0.f, N);
        int gE = (nTot + 255) / 256;
        k_gat_max<<<gE, 256, 0, stream>>>(sj, si, nE, nTot, esb, edb, mx);
        k_gat_den<<<gE, 256, 0, stream>>>(sj, si, nE, nTot, esb, edb, mx, ebuf, den);
        k_bias_init<<<gNH, 256, 0, stream>>>(outb, b_, N * H);
        k_gat_agg<<<(nTot + 3) / 4, 256, 0, stream>>>(sj, si, nE, nTot, hs, ebuf, den, outb);
        k_relu<<<gNH, 256, 0, stream>>>(outb, N * H);
    };

    // layer 0 (FIN->H)
    gat(x1_in, x1_in, true, ei_intra1, EIA_D, true, g0_w, g0_w, g0_as, g0_ad, g0_b, FIN_D, x1a);
    gat(x2_in, x2_in, true, ei_intra2, EIA_D, true, g0_w + FIN_D * H, g0_w + FIN_D * H,
        g0_as + H, g0_ad + H, g0_b + H, FIN_D, x2a);
    const float* cx1 = x1a;
    const float* cx2 = x2a;
    // layer 1 (H->H)
    gat(cx1, cx1, true, ei_intra1, EIA_D, true, g1_w, g1_w, g1_as, g1_ad, g1_b, H, x1b);
    gat(cx2, cx2, true, ei_intra2, EIA_D, true, g1_w + H * H, g1_w + H * H,
        g1_as + H, g1_ad + H, g1_b + H, H, x2b);
    cx1 = x1b; cx2 = x2b;
    // cross layers
    {
        float* outs1[2] = {x1a, x1b};
        float* outs2[2] = {x2a, x2b};
        for (int l = 0; l < 2; ++l) {
            int p0 = l * 2 + 0, p1 = l * 2 + 1;
            float* o2 = outs2[l == 0 ? 0 : 1];
            float* o1 = outs1[l == 0 ? 0 : 1];
            // nx2: src=x1, dst=x2, edges ei_12
            gat(cx1, cx2, false, ei_12, EIR_D, false,
                it_ws + (size_t)p0 * H * H, it_wd + (size_t)p0 * H * H,
                it_as + p0 * H, it_ad + p0 * H, it_b + p0 * H, H, o2);
            // nx1: src=x2, dst=x1, edges ei_21
            gat(cx2, cx1, false, ei_21, EIR_D, false,
                it_ws + (size_t)p1 * H * H, it_wd + (size_t)p1 * H * H,
                it_as + p1 * H, it_ad + p1 * H, it_b + p1 * H, H, o1);
            cx1 = o1; cx2 = o2;
        }
    }

    // ---- EGNN stage ----
    auto egnn = [&](const float* feats, const float* coors, const int* eiBase, int pidx,
                    float* featsOut, float* coorsOut) {
        const int* sj = eiBase;
        const int* si = eiBase + EIA_D;
        const float* ew1 = eg_e_w1 + (size_t)pidx * EIN_D * EHID_D;
        k_gemm<0, false><<<gemm_grid_A, 256, 0, stream>>>(feats, ew1, nullptr, nullptr, Abuf, N, EHID_D, H);
        k_gemm<0, false><<<gemm_grid_A, 256, 0, stream>>>(feats, ew1 + (size_t)H * EHID_D, nullptr, nullptr, Bbuf, N, EHID_D, H);
        k_copy<<<(N * 3 + 255) / 256, 256, 0, stream>>>(coorsOut, coors, N * 3);
        k_fill<<<(N * M_D + 255) / 256, 256, 0, stream>>>(macc, 0.f, N * M_D);
        k_egnn_edge<<<4096, 256, 0, stream>>>(sj, si, EIA_D, Abuf, Bbuf, coors,
                                              ew1 + (size_t)256 * EHID_D, eg_e_b1 + pidx * EHID_D,
                                              eg_e_w2 + (size_t)pidx * EHID_D * M_D, eg_e_b2 + pidx * M_D,
                                              eg_c_w1 + pidx * M_D * 64, eg_c_b1 + pidx * 64,
                                              eg_c_w2 + pidx * 64, eg_c_b2 + pidx,
                                              coorsOut, macc);
        k_concat<<<(N * NIN_D + 255) / 256, 256, 0, stream>>>(catb, feats, macc, N);
        k_gemm<2, false><<<gemm_grid_nh, 256, 0, stream>>>(catb, eg_n_w1 + (size_t)pidx * NIN_D * NHID_D,
                                                           eg_n_b1 + pidx * NHID_D, nullptr, nh, N, NHID_D, NIN_D);
        k_gemm<0, true><<<gemm_grid_h, 256, 0, stream>>>(nh, eg_n_w2 + (size_t)pidx * NHID_D * H,
                                                         eg_n_b2 + pidx * H, feats, featsOut, N, H, NHID_D);
    };
    // l=0
    egnn(cx1, pos1, ei_intra1, 0, x1a, co1a);
    egnn(cx2, pos2, ei_intra2, 1, x2a, co2a);
    cx1 = x1a; cx2 = x2a;
    // l=1
    egnn(cx1, co1a, ei_intra1, 2, x1b, co1b);
    egnn(cx2, co2a, ei_intra2, 3, x2b, co2b);
    cx1 = x1b; cx2 = x2b;

    // ---- heads ----
    k_nodescore<<<gNW, 256, 0, stream>>>(cx1, lin_w, lin_b, dout, N);
    k_nodescore<<<gNW, 256, 0, stream>>>(cx2, lin_w, lin_b, dout + N, N);
    k_aux<<<(EIT_D + 31) / 32, 256, 0, stream>>>(cx1, cx2, ei_int, ei_int + EIT_D,
                                                 aux_w1, aux_b1, aux_w2, aux_b2,
                                                 dout + 2 * N, EIT_D);
}